// Round 21
// baseline (160.210 us; speedup 1.0000x reference)
//
#include <hip/hip_runtime.h>
#include <hip/hip_bf16.h>

#define BATCH 8192
#define IDIM 256
#define ODIM 256

#define NC 8
#define IPC 32            // i-values per K-chunk
#define THREADS 256
#define RG_TOT 4096       // (2*IDIM*KGRID)/8

typedef __attribute__((ext_vector_type(8))) short short8;
typedef __attribute__((ext_vector_type(4))) float float4v;
typedef __attribute__((ext_vector_type(16))) float float16v;
typedef __attribute__((ext_vector_type(4))) unsigned int uint4v;

#define INV2PI 0.15915494309189535f

// pack two f32 -> (bf16(c) | bf16(s)<<16), RTNE (prep_w only)
__device__ __forceinline__ unsigned int bf16pack(float c, float s) {
    union { float f; unsigned int u; } a, b;
    a.f = c; b.f = s;
    unsigned int ua = a.u + (0x7fffu + ((a.u >> 16) & 1u));
    unsigned int ub = b.u + (0x7fffu + ((b.u >> 16) & 1u));
    return (ua >> 16) | (ub & 0xffff0000u);
}

// single-instruction pack: lo = bf16(c), hi = bf16(s)
__device__ __forceinline__ unsigned int cvtpk(float c, float s) {
    unsigned int r;
    asm("v_cvt_pk_bf16_f32 %0, %1, %2" : "=v"(r) : "v"(c), "v"(s));
    return r;
}

__device__ __forceinline__ float16v mfma(short8 a, uint4v b, float16v c) {
    return __builtin_amdgcn_mfma_f32_32x32x16_bf16(
        a, __builtin_bit_cast(short8, b), c, 0, 0, 0);
}

// W[2][256][256][64] f32 -> Bw2 k-step slab layout (verified R12/R14..R20):
// [chunk][wn][s=256][g=2][jl=128] 16B-slots; one (chunk,wn) region = 1MB,
// one k-step slab = 4KB contiguous, one half-i = 4 slabs = 16KB.
__global__ void prep_w(const float4v* __restrict__ W, uint4v* __restrict__ Bw2) {
    int tid = blockIdx.x * 256 + threadIdx.x;   // 1,048,576 threads
    int rg = tid & 4095;
    int j = tid >> 12;
    float4v c4 = W[j * 4096 + rg];
    float4v s4 = W[1048576 + j * 4096 + rg];
    uint4v o;
    o.x = bf16pack(c4.x, s4.x);
    o.y = bf16pack(c4.y, s4.y);
    o.z = bf16pack(c4.z, s4.z);
    o.w = bf16pack(c4.w, s4.w);
    int chunk = rg >> 9, rl = rg & 511, s = rl >> 1, g = rl & 1;
    int wn = j >> 7, jl = j & 127;
    Bw2[((((size_t)(chunk * 2 + wn) * 256 + s) * 2 + g) << 7) + jl] = o;
}

// 4 waves/block, wave tile 32 rows x 128 cols: acc = 64 AGPR, arch VGPR
// forced <= 64 via __launch_bounds__(256,4) -> <=128 unified regs/wave ->
// 16 waves/CU (4 waves/SIMD) -- the occupancy cell R16 missed (its 132-reg
// waves silently fell back to 8/CU). All ILP machinery stripped (no reg
// ping-pong, no next-i trig pipelining): TLP at 4 waves/SIMD hides the
// latencies instead. Minimal-sync depth-2 half-i ring (32KB LDS -> 4
// blocks/CU): one vmcnt(0)+barrier+STAGE per phase, R20-verified protocol.
__global__ __launch_bounds__(THREADS, 4) void kan_main(
    const float* __restrict__ x,
    const char* __restrict__ Bw2,
    unsigned short* __restrict__ part)
{
    __shared__ __align__(16) uint4v ring[2][4][256];   // 32 KB

    const int bx = blockIdx.x;
    const int chunk = bx & 7;          // K-chunk == XCD id (1024 blocks)
    const int wn = (bx >> 3) & 1;      // 128-col half
    const int mb = bx >> 4;            // M-block 0..63 (128 rows)
    const int b0 = mb * 128;
    const int i0 = chunk * IPC;
    const int t = threadIdx.x;
    const int lane = t & 63;
    const int wave = t >> 6;           // 0..3 -> 32-row slice
    const int g = lane >> 5;           // k-octet half
    const int l31 = lane & 31;

    const int row = b0 + wave * 32 + l31;
    const float* xr = x + (size_t)row * IDIM + i0;

    // ---- B staging pointers (verified R14) ----
    const char* gq = Bw2 + ((size_t)(chunk * 2 + wn) << 20)
                   + wave * 1024 + (size_t)lane * 16;
    char* lds0 = (char*)&ring[0][0][0] + wave * 1024;

    // prologue: stage phase 0 into slot 0 (4 loads outstanding)
    #pragma unroll
    for (int u = 0; u < 4; ++u)
        __builtin_amdgcn_global_load_lds(
            (const __attribute__((address_space(1))) void*)(gq + u * 4096),
            (__attribute__((address_space(3))) void*)(lds0 + u * 4096),
            16, 0, 0);
    gq += 16384;

    float16v acc[4];
    #pragma unroll
    for (int f = 0; f < 4; ++f) acc[f] = (float16v)(0.0f);

    const float mbase = (float)(4 * g + 1);

    for (int p = 0; p < IPC; ++p) {
        float c0[4], s0[4], c8, s8;

        // ---------- PHASE A: k-steps 0..3, slot p&1... = (2p)&1 = 0 ----------
        asm volatile("s_waitcnt vmcnt(0)" ::: "memory");
        asm volatile("s_barrier" ::: "memory");
        // stage phase 2p+1 into slot 1 (read-done proven by the barrier)
        #pragma unroll
        for (int u = 0; u < 4; ++u)
            __builtin_amdgcn_global_load_lds(
                (const __attribute__((address_space(1))) void*)(gq + u * 4096),
                (__attribute__((address_space(3))) void*)(lds0 + 16384 + u * 4096),
                16, 0, 0);
        gq += 16384;

        // trig init for this i (serial trans chain covered by 4-wave TLP)
        {
            const float xk = xr[p] * INV2PI;
            #pragma unroll
            for (int u = 0; u < 4; ++u) {
                float r = __builtin_amdgcn_fractf(xk * (mbase + (float)u));
                c0[u] = __builtin_amdgcn_cosf(r);
                s0[u] = __builtin_amdgcn_sinf(r);
            }
            float tt = __builtin_amdgcn_fractf(8.0f * xk);
            c8 = __builtin_amdgcn_cosf(tt);
            s8 = __builtin_amdgcn_sinf(tt);
        }

        #define KSTEP(SB, Q, DOROT) do {                            \
            const uint4v* sk_ = (SB) + (Q) * 256;                   \
            uint4v bf0_ = sk_[0];                                   \
            uint4v bf1_ = sk_[32];                                  \
            uint4v bf2_ = sk_[64];                                  \
            uint4v bf3_ = sk_[96];                                  \
            uint4v w_;                                              \
            _Pragma("unroll") for (int u_ = 0; u_ < 4; ++u_)        \
                w_[u_] = cvtpk(c0[u_], s0[u_]);                     \
            short8 a_ = __builtin_bit_cast(short8, w_);             \
            __builtin_amdgcn_s_setprio(1);                          \
            acc[0] = mfma(a_, bf0_, acc[0]);                        \
            acc[1] = mfma(a_, bf1_, acc[1]);                        \
            acc[2] = mfma(a_, bf2_, acc[2]);                        \
            acc[3] = mfma(a_, bf3_, acc[3]);                        \
            __builtin_amdgcn_s_setprio(0);                          \
            if (DOROT) {                                            \
                _Pragma("unroll") for (int u_ = 0; u_ < 4; ++u_) {  \
                    float cn_ = fmaf(-s0[u_], s8, c0[u_] * c8);     \
                    float sn_ = fmaf( c0[u_], s8, s0[u_] * c8);     \
                    c0[u_] = cn_; s0[u_] = sn_;                     \
                } }                                                 \
        } while (0)

        {
            const uint4v* sb = &ring[0][0][g * 128 + l31];
            KSTEP(sb, 0, 1);
            KSTEP(sb, 1, 1);
            KSTEP(sb, 2, 1);
            KSTEP(sb, 3, 1);
        }

        // ---------- PHASE B: k-steps 4..7, slot 1 ----------
        asm volatile("s_waitcnt vmcnt(0)" ::: "memory");
        asm volatile("s_barrier" ::: "memory");
        // stage phase 2p+2 into slot 0 (tail overruns 16KB into part buffer:
        // loaded, never consumed)
        #pragma unroll
        for (int u = 0; u < 4; ++u)
            __builtin_amdgcn_global_load_lds(
                (const __attribute__((address_space(1))) void*)(gq + u * 4096),
                (__attribute__((address_space(3))) void*)(lds0 + u * 4096),
                16, 0, 0);
        gq += 16384;

        {
            const uint4v* sb = &ring[1][0][g * 128 + l31];
            KSTEP(sb, 0, 1);
            KSTEP(sb, 1, 1);
            KSTEP(sb, 2, 1);
            KSTEP(sb, 3, 0);
        }
        #undef KSTEP
    }

    // drain in-flight LDS-writing loads before exit (next block reuses LDS)
    asm volatile("s_waitcnt vmcnt(0)" ::: "memory");

    // ---- store partials as bf16: part[chunk][b][j] ----
    // 32x32 C/D (verified R4..R20): col = lane&31,
    // row = (v&3) + 8*(v>>2) + 4*(lane>>5)
    const int cb = wn * 128 + l31;
    const int rb = b0 + wave * 32 + 4 * g;
    unsigned short* pc = part + (size_t)chunk * (BATCH * ODIM);
    #pragma unroll
    for (int f = 0; f < 4; ++f)
        #pragma unroll
        for (int v = 0; v < 16; ++v) {
            int r = rb + (v & 3) + 8 * (v >> 2);
            pc[(size_t)r * ODIM + cb + f * 32] =
                (unsigned short)cvtpk(acc[f][v], 0.0f);
        }
}

// sum 8 bf16 partials + bias -> f32 out; 8 elements per thread
__global__ void reduce_bias(const short8* __restrict__ part,
                            const float* __restrict__ bias,
                            float4v* __restrict__ out)
{
    const int tid = blockIdx.x * 256 + threadIdx.x;   // 262144 threads
    const int Q = BATCH * ODIM / 8;
    float a8[8];
    #pragma unroll
    for (int e = 0; e < 8; ++e) a8[e] = 0.0f;
    #pragma unroll
    for (int c = 0; c < NC; ++c) {
        short8 v = part[c * Q + tid];
        #pragma unroll
        for (int e = 0; e < 8; ++e) {
            union { unsigned int u; float f; } cv;
            cv.u = ((unsigned int)(unsigned short)v[e]) << 16;
            a8[e] += cv.f;
        }
    }
    const int jb = (tid * 8) & 255;
    const float4v* b4 = (const float4v*)(bias + jb);
    float4v bb0 = b4[0], bb1 = b4[1];
    float4v o0, o1;
    o0.x = a8[0] + bb0.x; o0.y = a8[1] + bb0.y;
    o0.z = a8[2] + bb0.z; o0.w = a8[3] + bb0.w;
    o1.x = a8[4] + bb1.x; o1.y = a8[5] + bb1.y;
    o1.z = a8[6] + bb1.z; o1.w = a8[7] + bb1.w;
    out[tid * 2] = o0;
    out[tid * 2 + 1] = o1;
}

extern "C" void kernel_launch(void* const* d_in, const int* in_sizes, int n_in,
                              void* d_out, int out_size, void* d_ws, size_t ws_size,
                              hipStream_t stream)
{
    const float* x = (const float*)d_in[0];
    const float* W = (const float*)d_in[1];
    const float* bias = (const float*)d_in[2];
    float* out = (float*)d_out;

    const size_t bw_bytes = (size_t)RG_TOT * 256 * 16;   // 16.78 MB (16B-aligned)

    char* Bw2 = (char*)d_ws;
    unsigned short* part = (unsigned short*)((char*)d_ws + bw_bytes);  // 33.5 MB bf16

    prep_w<<<4096, 256, 0, stream>>>((const float4v*)W, (uint4v*)Bw2);
    // 1024 blocks x 256 thr; LDS 32KB -> 4 blocks/CU; <=128 regs -> 16 waves/CU
    kan_main<<<(BATCH / 128) * 2 * NC, THREADS, 0, stream>>>(x, Bw2, part);
    reduce_bias<<<(BATCH * ODIM / 8) / 256, 256, 0, stream>>>(
        (const short8*)part, bias, (float4v*)out);
}